// Round 3
// baseline (846.240 us; speedup 1.0000x reference)
//
#include <hip/hip_runtime.h>
#include <hip/hip_bf16.h>

// Problem shape (fixed by reference setup_inputs)
constexpr int MM = 4096;   // tokens
constexpr int NN = 8192;   // outfeatures
constexpr int KK = 8192;   // infeatures
constexpr int BM = 256, BN = 256, BK = 64;
constexpr int THREADS = 256;   // 4 waves in 2x2; wave tile 128x128
constexpr int NKB = KK / BK;   // 128
constexpr int NT = NN / BN;    // 32

typedef __bf16 bf16;
typedef __attribute__((ext_vector_type(8))) __bf16 bf16x8;
typedef __attribute__((ext_vector_type(4))) float floatx4;
typedef __attribute__((ext_vector_type(16))) float floatx16;

__device__ __forceinline__ void async_copy16(const void* g, void* l) {
    __builtin_amdgcn_global_load_lds(
        (const __attribute__((address_space(1))) void*)g,
        (__attribute__((address_space(3))) void*)l, 16, 0, 0);
}

// ---------------------------------------------------------------------------
// Prep: x fp32 -> bf16, re-laid-out FRAG-MAJOR:
//   xb chunk index (16B units) = ((mt*128 + kb)*2048) + ((wmh*4+im)*4+ks)*64 + lane
// holding A[m = mt*256 + wmh*128 + im*32 + (lane&31)]
//          [k = kb*64 + ks*16 + (lane>>5)*8 + j],  j = 0..7.
// Each (mt,kb) A-tile (32 KB) is byte-identical to its LDS image; every
// ds_read_b128 in the GEMM is lane-linear (conflict-free by construction).
// ---------------------------------------------------------------------------
__global__ __launch_bounds__(256)
void convert_x(const float* __restrict__ x, bf16* __restrict__ xb) {
    const int c = blockIdx.x * 256 + threadIdx.x;   // one 16B output chunk
    const int lane = c & 63;
    const int ks   = (c >> 6) & 3;
    const int im   = (c >> 8) & 3;
    const int wmh  = (c >> 10) & 1;
    const int kb   = (c >> 11) & 127;
    const int mt   = c >> 18;
    const int m = mt * 256 + wmh * 128 + im * 32 + (lane & 31);
    const int k = kb * 64 + ks * 16 + (lane >> 5) * 8;
    const float4* src = (const float4*)(x + (size_t)m * KK + k);
    const float4 f0 = src[0];
    const float4 f1 = src[1];
    bf16x8 v;
    v[0] = (bf16)f0.x; v[1] = (bf16)f0.y; v[2] = (bf16)f0.z; v[3] = (bf16)f0.w;
    v[4] = (bf16)f1.x; v[5] = (bf16)f1.y; v[6] = (bf16)f1.z; v[7] = (bf16)f1.w;
    *(bf16x8*)(xb + (size_t)c * 8) = v;
}

// ---------------------------------------------------------------------------
// Main GEMM: 4 waves, wave tile 128x128, mfma_f32_32x32x16_bf16.
// Double-buffered LDS (A via DMA, B inline-dequant), one barrier per K-block.
// LDS layout is frag-major for both A and B: offset = frag_idx*1024 + lane*16.
// ---------------------------------------------------------------------------
__global__ __launch_bounds__(THREADS, 1)
void qgemm_big(const bf16* __restrict__ xb,
               const unsigned* __restrict__ qweight,
               const unsigned* __restrict__ qzeros,
               const float* __restrict__ scales,
               const float* __restrict__ bias,
               float* __restrict__ out)
{
    __shared__ alignas(16) bf16 As[2][BM * BK];   // 2 x 32 KB
    __shared__ alignas(16) bf16 Bs[2][BN * BK];   // 2 x 32 KB

    const int t = threadIdx.x;
    const int ntile = blockIdx.x & (NT - 1);   // n fastest: share x m-tile
    const int mtile = blockIdx.x / NT;
    const int n0 = ntile * BN;

    const int wave = t >> 6;
    const int lane = t & 63;
    const int wmh = wave >> 1;          // 0/1: M half (128 rows)
    const int nfb = (wave & 1) * 4;     // B n-frag base (4 frags of 32 cols)

    // B staging: thread owns one output column, all 8 k-octets of the K-block
    const int nf = t >> 5;              // n-frag 0..7
    const int nl = t & 31;              // col within frag
    const int gn = n0 + t;

    floatx16 acc[4][4];
#pragma unroll
    for (int i = 0; i < 4; ++i)
#pragma unroll
        for (int j = 0; j < 4; ++j)
            acc[i][j] = (floatx16)0.f;

    const char* xb_base = (const char*)xb + (size_t)mtile * NKB * 32768;

    unsigned bq[8];
    float s = 0.f, sz = 0.f;

    auto stage_a = [&](int kb, int buf) {
        const char* g = xb_base + (size_t)kb * 32768 + wave * 8192 + lane * 16;
        char* l = (char*)&As[buf][0] + wave * 8192;
#pragma unroll
        for (int i = 0; i < 8; ++i)
            async_copy16(g + i * 1024, l + i * 1024);
    };
    auto load_b = [&](int kb) {
#pragma unroll
        for (int r = 0; r < 8; ++r)
            bq[r] = qweight[(size_t)(kb * 8 + r) * NN + gn];
    };
    // one qweight word = one lane-fragment: k-octet r -> frag ks=r>>1, half r&1
    auto store_b = [&](int buf) {
#pragma unroll
        for (int r = 0; r < 8; ++r) {
            const unsigned q = bq[r];
            bf16x8 v;
#pragma unroll
            for (int j = 0; j < 8; ++j)
                v[j] = (bf16)((float)((q >> (4 * j)) & 15u) * s - sz);
            *(bf16x8*)&Bs[buf][(((nf * 4 + (r >> 1)) * 64) + (r & 1) * 32 + nl) * 8] = v;
        }
    };
    auto compute_ks = [&](int buf, int ks) {
        bf16x8 af[4], bfr[4];
#pragma unroll
        for (int im = 0; im < 4; ++im)
            af[im] = *(const bf16x8*)&As[buf][(((wmh * 4 + im) * 4 + ks) * 64 + lane) * 8];
#pragma unroll
        for (int jn = 0; jn < 4; ++jn)
            bfr[jn] = *(const bf16x8*)&Bs[buf][(((nfb + jn) * 4 + ks) * 64 + lane) * 8];
#pragma unroll
        for (int im = 0; im < 4; ++im)
#pragma unroll
            for (int jn = 0; jn < 4; ++jn)
                acc[im][jn] = __builtin_amdgcn_mfma_f32_32x32x16_bf16(
                    af[im], bfr[jn], acc[im][jn], 0, 0, 0);
    };

    // --- prologue: stage kb=0 into buf 0 ---
    {
        s = scales[gn];
        const unsigned zw = qzeros[gn >> 3];
        sz = s * (float)(((zw >> (4 * (gn & 7))) & 15u) + 1u);
        stage_a(0, 0);
        load_b(0);
        store_b(0);
    }
    __syncthreads();

    float s_nxt = 0.f;
    unsigned zw_nxt = 0;
    for (int kb = 0; kb < NKB; ++kb) {
        const int p = kb & 1, q = p ^ 1;
        const bool has_next = (kb + 1) < NKB;
        if (has_next) {
            stage_a(kb + 1, q);              // DMA into other buffer
            load_b(kb + 1);                  // raw qweight into regs
            if (((kb + 1) & 1) == 0) {       // group changes every 2 K-blocks
                const int g = (kb + 1) >> 1;
                s_nxt = scales[(size_t)g * NN + gn];
                zw_nxt = qzeros[(size_t)g * (NN / 8) + (gn >> 3)];
            }
        }
        // interleave dequant-store into the middle of compute: keeps the
        // matrix pipe fed while the VALU does the unpack.
        compute_ks(p, 0);
        compute_ks(p, 1);
        if (has_next) {
            if (((kb + 1) & 1) == 0) {
                s = s_nxt;
                sz = s * (float)(((zw_nxt >> (4 * (gn & 7))) & 15u) + 1u);
            }
            store_b(q);
        }
        compute_ks(p, 2);
        compute_ks(p, 3);
        if (has_next)
            __syncthreads();                 // single barrier per K-block
    }

    // --- epilogue: 32x32 C/D layout col=lane&31, row=(reg&3)+8*(reg>>2)+4*(lane>>5) ---
#pragma unroll
    for (int jn = 0; jn < 4; ++jn) {
        const int ngl = n0 + (wave & 1) * 128 + jn * 32 + (lane & 31);
        const float bv = bias[ngl];
#pragma unroll
        for (int im = 0; im < 4; ++im) {
            const int mbase = mtile * BM + wmh * 128 + im * 32 + 4 * (lane >> 5);
            const floatx16 a = acc[im][jn];
#pragma unroll
            for (int reg = 0; reg < 16; ++reg) {
                const int mg = mbase + (reg & 3) + 8 * (reg >> 2);
                out[(size_t)mg * NN + ngl] = a[reg] + bv;
            }
        }
    }
}

// ---------------------------------------------------------------------------
// Fallback (round-2-class single-kernel path): used only if ws too small.
// ---------------------------------------------------------------------------
__global__ __launch_bounds__(512, 2)
void qgemm_fallback(const float* __restrict__ x,
                    const unsigned* __restrict__ qweight,
                    const unsigned* __restrict__ qzeros,
                    const float* __restrict__ scales,
                    const float* __restrict__ bias,
                    float* __restrict__ out)
{
    __shared__ bf16 As[BM * BK];
    __shared__ bf16 Bs[BN * BK];

    const int t = threadIdx.x;
    const int ntile = blockIdx.x & 31;
    const int mtile = blockIdx.x >> 5;
    const int m0 = mtile * BM;
    const int n0 = ntile * BN;
    const int wave = t >> 6;
    const int lane = t & 63;
    const int wm = (wave >> 1) * 64;
    const int wn = (wave & 1) * 128;
    const int ml = lane & 15;
    const int quad = lane >> 4;
    const int bn = t & 255;
    const int rbase = (t >> 8) * 4;
    const int gn = n0 + bn;

    floatx4 acc[4][8];
    for (int i = 0; i < 4; ++i)
        for (int j = 0; j < 8; ++j)
            acc[i][j] = (floatx4){0.f, 0.f, 0.f, 0.f};

    float s = 0.f, sz = 0.f;

    for (int kb = 0; kb < KK / BK; ++kb) {
        const int k0 = kb * BK;
        if ((kb & 1) == 0) {
            const int g = kb >> 1;
            s = scales[g * NN + gn];
            const unsigned zw = qzeros[g * (NN / 8) + (gn >> 3)];
            sz = s * (float)(((zw >> (4 * (gn & 7))) & 15u) + 1u);
        }
#pragma unroll
        for (int i = 0; i < 4; ++i) {
            const int chunk = t + 512 * i;
            const int m = chunk >> 3;
            const int c = chunk & 7;
            const float4* src = (const float4*)(x + (size_t)(m0 + m) * KK + (k0 + c * 8));
            const float4 f0 = src[0];
            const float4 f1 = src[1];
            bf16x8 v;
            v[0] = (bf16)f0.x; v[1] = (bf16)f0.y; v[2] = (bf16)f0.z; v[3] = (bf16)f0.w;
            v[4] = (bf16)f1.x; v[5] = (bf16)f1.y; v[6] = (bf16)f1.z; v[7] = (bf16)f1.w;
            *(bf16x8*)&As[m * BK + ((c ^ (m & 7)) << 3)] = v;
        }
        const int kq0 = k0 >> 3;
#pragma unroll
        for (int i = 0; i < 4; ++i) {
            const int rq = rbase + i;
            const unsigned q = qweight[(size_t)(kq0 + rq) * NN + gn];
            bf16x8 v;
#pragma unroll
            for (int j = 0; j < 8; ++j)
                v[j] = (bf16)((float)((q >> (4 * j)) & 15u) * s - sz);
            *(bf16x8*)&Bs[bn * BK + ((rq ^ (bn & 7)) << 3)] = v;
        }
        __syncthreads();
#pragma unroll
        for (int ks = 0; ks < 2; ++ks) {
            const int clog = ks * 4 + quad;
            bf16x8 af[4];
            bf16x8 bfr[8];
#pragma unroll
            for (int im = 0; im < 4; ++im) {
                const int row = wm + im * 16 + ml;
                af[im] = *(const bf16x8*)&As[row * BK + ((clog ^ (row & 7)) << 3)];
            }
#pragma unroll
            for (int jn = 0; jn < 8; ++jn) {
                const int row = wn + jn * 16 + ml;
                bfr[jn] = *(const bf16x8*)&Bs[row * BK + ((clog ^ (row & 7)) << 3)];
            }
#pragma unroll
            for (int im = 0; im < 4; ++im)
#pragma unroll
                for (int jn = 0; jn < 8; ++jn)
                    acc[im][jn] = __builtin_amdgcn_mfma_f32_16x16x32_bf16(
                        af[im], bfr[jn], acc[im][jn], 0, 0, 0);
        }
        __syncthreads();
    }
#pragma unroll
    for (int jn = 0; jn < 8; ++jn) {
        const int ngl = n0 + wn + jn * 16 + ml;
        const float bv = bias[ngl];
#pragma unroll
        for (int im = 0; im < 4; ++im) {
            const int mg = m0 + wm + im * 16 + quad * 4;
#pragma unroll
            for (int r = 0; r < 4; ++r)
                out[(size_t)(mg + r) * NN + ngl] = acc[im][jn][r] + bv;
        }
    }
}

extern "C" void kernel_launch(void* const* d_in, const int* in_sizes, int n_in,
                              void* d_out, int out_size, void* d_ws, size_t ws_size,
                              hipStream_t stream) {
    const float*    x       = (const float*)d_in[0];
    const unsigned* qweight = (const unsigned*)d_in[1];
    const unsigned* qzeros  = (const unsigned*)d_in[2];
    const float*    scales  = (const float*)d_in[3];
    const float*    bias    = (const float*)d_in[4];
    float* out = (float*)d_out;

    const size_t xb_bytes = (size_t)MM * KK * sizeof(bf16);   // 67 MB

    if (ws_size >= xb_bytes) {
        bf16* xb = (bf16*)d_ws;
        const int chunks = MM * KK / 8;       // 4,194,304 16B chunks
        convert_x<<<chunks / 256, 256, 0, stream>>>(x, xb);
        const int grid = (MM / BM) * (NN / BN);   // 512 blocks
        qgemm_big<<<grid, THREADS, 0, stream>>>(xb, qweight, qzeros, scales, bias, out);
    } else {
        const int grid = (MM / BM) * (NN / BN);
        qgemm_fallback<<<grid, 512, 0, stream>>>(x, qweight, qzeros, scales, bias, out);
    }
}